// Round 8
// baseline (192.689 us; speedup 1.0000x reference)
//
#include <hip/hip_runtime.h>
#include <math.h>
#include <stdint.h>

#define B 4
#define T 8192
#define D 512
#define NN 256
#define L 768
#define TE 2048
#define H 8
#define DH 64
#define MR 32           // rows per k_main block
#define AS 520          // Abuf row stride (bf16 elems)
#define SLICE 16384     // elems per 32-K staged B slice (512 cols * 32 k)

typedef __bf16 bf16;
typedef bf16  bf16x8 __attribute__((ext_vector_type(8)));
typedef float f32x4  __attribute__((ext_vector_type(4)));

__device__ __forceinline__ float sigmoidf_(float x){ return 1.0f/(1.0f+__expf(-x)); }

// ======== fused prep (unchanged from r7) ========
__global__ __launch_bounds__(256) void k_prep(
    const float* __restrict__ Wq, const float* __restrict__ oW,
    bf16* __restrict__ wqS, bf16* __restrict__ owS,
    const float* __restrict__ emb, const float* __restrict__ emb_W,
    const float* __restrict__ emb_b, float* __restrict__ ss,
    const float* __restrict__ xf, const float* __restrict__ Wk,
    const float* __restrict__ bk, const float* __restrict__ Wv,
    const float* __restrict__ bv, const float* __restrict__ tg,
    const float* __restrict__ tb, bf16* __restrict__ kbuf, bf16* __restrict__ vbuf){
    __shared__ __align__(16) char smem[49408];
    const int bid = blockIdx.x, t = threadIdx.x;
    if (bid < 128){
        const float* W = (bid < 64) ? Wq : oW;
        bf16* Wst = (bid < 64) ? wqS : owS;
        int lb = bid & 63;
        int k0 = (lb & 7)*64, n0 = (lb >> 3)*64;
        float (*tile)[65] = (float(*)[65])smem;
        int c = t & 63, r4 = t >> 6;
        #pragma unroll
        for (int p = 0; p < 16; ++p){ int r = p*4 + r4; tile[r][c] = W[(size_t)(k0+r)*D + n0 + c]; }
        __syncthreads();
        int oct = t >> 6, col = t & 63;
        #pragma unroll
        for (int half = 0; half < 2; ++half){
            int kk = (lb & 7)*2 + half;
            bf16x8 ov;
            #pragma unroll
            for (int j = 0; j < 8; ++j) ov[j] = (bf16)tile[half*32 + oct*8 + j][col];
            *(bf16x8*)&Wst[(size_t)kk*SLICE + (n0+col)*32 + oct*8] = ov;
        }
    } else if (bid < 192){
        float (*semb)[TE] = (float(*)[TE])smem;
        float (*red)[64]  = (float(*)[64])(smem + 4*TE*4);
        int c = bid - 128;
        for (int i = t; i < TE; i += 256)
            #pragma unroll
            for (int b = 0; b < B; ++b){ float e = emb[b*TE + i]; semb[b][i] = e * sigmoidf_(e); }
        __syncthreads();
        int o = t & 15, p = t >> 4;
        int j = c*16 + o;
        float acc[B] = {0.f,0.f,0.f,0.f};
        for (int i = 0; i < 128; ++i){
            int e = p*128 + i;
            float wv = emb_W[(size_t)e*1024 + j];
            #pragma unroll
            for (int b = 0; b < B; ++b) acc[b] += semb[b][e] * wv;
        }
        #pragma unroll
        for (int b = 0; b < B; ++b) red[p][b*16 + o] = acc[b];
        __syncthreads();
        if (t < 64){
            int b = t >> 4, o2 = t & 15;
            int j2 = c*16 + o2;
            float s = 0.f;
            #pragma unroll
            for (int pp = 0; pp < 16; ++pp) s += red[pp][b*16 + o2];
            ss[b*1024 + j2] = s + emb_b[j2];
        }
    } else {
        float (*xfn)[L] = (float(*)[L])smem;
        int lb = bid - 192;
        int g0 = (lb >> 2) * 16, jc = lb & 3;
        int wave = t >> 6, lane = t & 63;
        #pragma unroll
        for (int rr = 0; rr < 4; ++rr){
            int r = wave*4 + rr, g = g0 + r;
            float vals[12];
            float s = 0.f, sq = 0.f;
            #pragma unroll
            for (int i = 0; i < 12; ++i){ float v = xf[(size_t)g*L + lane*12 + i]; vals[i] = v; s += v; sq += v*v; }
            #pragma unroll
            for (int o = 32; o; o >>= 1){ s += __shfl_xor(s, o); sq += __shfl_xor(sq, o); }
            float m = s / L; float var = sq / L - m*m;
            float rstd = rsqrtf(var + 1e-5f);
            #pragma unroll
            for (int i = 0; i < 12; ++i){
                int l = lane*12 + i;
                xfn[r][l] = (vals[i]-m)*rstd*tg[l] + tb[l];
            }
        }
        __syncthreads();
        const float* Wm = (t < 128) ? Wk : Wv;
        int col = jc*128 + (t & 127);
        float acc[16];
        #pragma unroll
        for (int r = 0; r < 16; ++r) acc[r] = 0.f;
        for (int l = 0; l < L; l += 4){
            float4 xv[16];
            #pragma unroll
            for (int r = 0; r < 16; ++r) xv[r] = *(const float4*)&xfn[r][l];
            #pragma unroll
            for (int u = 0; u < 4; ++u){
                float wv = Wm[(size_t)(l+u)*D + col];
                #pragma unroll
                for (int r = 0; r < 16; ++r) acc[r] += ((const float*)&xv[r])[u] * wv;
            }
        }
        float bias = (t < 128) ? bk[col] : bv[col];
        bf16* dst = (t < 128) ? kbuf : vbuf;
        #pragma unroll
        for (int r = 0; r < 16; ++r){
            size_t g = (size_t)(g0 + r);
            dst[g*D + col] = (bf16)(acc[r] + bias);
        }
    }
}

// ======== k-softmax + state (unchanged from r7) ========
__global__ void k_att(const bf16* __restrict__ kbuf, const bf16* __restrict__ vbuf,
                      bf16* __restrict__ attF){
    __shared__ float kh[NN*DH];
    __shared__ float vh[NN*DH];
    __shared__ float pm[4][DH], ps[4][DH];
    int t = threadIdx.x, h = blockIdx.x, b = blockIdx.y;
    for (int k = 0; k < NN*DH/256; ++k){
        int m = k*256 + t;
        int n = m >> 6, dl = m & 63;
        size_t src = (size_t)(b*NN + n)*D + h*DH + dl;
        kh[m] = (float)kbuf[src]; vh[m] = (float)vbuf[src];
    }
    __syncthreads();
    int d = t & 63, c = t >> 6;
    float mx = -1e30f;
    for (int n = c*64; n < c*64+64; ++n) mx = fmaxf(mx, kh[n*DH + d]);
    pm[c][d] = mx;
    __syncthreads();
    mx = fmaxf(fmaxf(pm[0][d], pm[1][d]), fmaxf(pm[2][d], pm[3][d]));
    float s = 0.f;
    for (int n = c*64; n < c*64+64; ++n){ float e = __expf(kh[n*DH + d] - mx); kh[n*DH + d] = e; s += e; }
    ps[c][d] = s;
    __syncthreads();
    float inv = 1.f/(ps[0][d] + ps[1][d] + ps[2][d] + ps[3][d]);
    for (int n = c*64; n < c*64+64; ++n) kh[n*DH + d] *= inv;
    __syncthreads();
    int l = t >> 2, dd0 = (t & 3)*16;
    float acc[16];
    #pragma unroll
    for (int i = 0; i < 16; ++i) acc[i] = 0.f;
    for (int n = 0; n < NN; ++n){
        float vv = vh[n*DH + l];
        #pragma unroll
        for (int i = 0; i < 16; ++i) acc[i] += kh[n*DH + dd0 + i] * vv;
    }
    size_t hbase = ((size_t)(b*H + h)) << 12;
    #pragma unroll
    for (int half = 0; half < 2; ++half){
        int d0 = dd0 + half*8;
        int f  = (l >> 4)*2 + (d0 >> 5);
        int ln = ((d0 >> 3) & 3)*16 + (l & 15);
        bf16x8 ov;
        #pragma unroll
        for (int j = 0; j < 8; ++j) ov[j] = (bf16)acc[half*8 + j];
        *(bf16x8*)&attF[hbase + f*512 + ln*8] = ov;
    }
}

// ======== rolled GEMM, nt=8 (2 heads), half-slice ping-pong B prefetch ========
__device__ __forceinline__ void gemm_body(const bf16* __restrict__ wfrag,
                                          const bf16* __restrict__ afrag,
                                          f32x4 (&acc)[2][8]){
    bf16x8 bA[4], bB[4];
    #pragma unroll
    for (int nt = 0; nt < 4; ++nt) bA[nt] = *(const bf16x8*)&wfrag[nt*512];
    #pragma unroll
    for (int nt = 0; nt < 4; ++nt) bB[nt] = *(const bf16x8*)&wfrag[2048 + nt*512];
    const bf16* wp = wfrag;
    const bf16* ap = afrag;
    for (int kk = 0; kk < 16; ++kk){
        bf16x8 aa[2];
        #pragma unroll
        for (int mt = 0; mt < 2; ++mt) aa[mt] = *(const bf16x8*)&ap[mt*16*AS];
        // half 0: nt 0..3 (head 2w)
        #pragma unroll
        for (int nt = 0; nt < 4; ++nt)
            #pragma unroll
            for (int mt = 0; mt < 2; ++mt)
                acc[mt][nt] = __builtin_amdgcn_mfma_f32_16x16x32_bf16(aa[mt], bA[nt], acc[mt][nt], 0, 0, 0);
        if (kk < 15){
            #pragma unroll
            for (int nt = 0; nt < 4; ++nt) bA[nt] = *(const bf16x8*)&wp[SLICE + nt*512];
        }
        // half 1: nt 4..7 (head 2w+1)
        #pragma unroll
        for (int nt = 0; nt < 4; ++nt)
            #pragma unroll
            for (int mt = 0; mt < 2; ++mt)
                acc[mt][4+nt] = __builtin_amdgcn_mfma_f32_16x16x32_bf16(aa[mt], bB[nt], acc[mt][4+nt], 0, 0, 0);
        if (kk < 15){
            #pragma unroll
            for (int nt = 0; nt < 4; ++nt) bB[nt] = *(const bf16x8*)&wp[SLICE + 2048 + nt*512];
        }
        wp += SLICE; ap += 32;
    }
}

// ======== main fused kernel: 32 rows/block, 4 waves (2 heads each), 4 blocks/CU ========
__global__ __launch_bounds__(256, 4) void k_main(
    const float* __restrict__ x, const bf16* __restrict__ WqS, const float* __restrict__ bq,
    const float* __restrict__ lg, const float* __restrict__ lb,
    const bf16* __restrict__ attF, const float* __restrict__ ssb,
    const float* __restrict__ sg, const float* __restrict__ sb,
    const bf16* __restrict__ oWS, const float* __restrict__ ob,
    float* __restrict__ out){
    __shared__ __align__(16) bf16 Abuf[MR*AS];      // 33.3 KB
    __shared__ float st_s[MR][4];
    __shared__ float st_q[MR][4];
    const int t = threadIdx.x, w = t >> 6, lane = t & 63;
    const int l15 = lane & 15, grp = lane >> 4;
    const long g0 = (long)blockIdx.x * MR;
    const int b = (int)(g0 / T);
    const int wb = w * 128;      // wave's 128-col slab = heads 2w, 2w+1
    const size_t fragoff = (size_t)wb*32 + (size_t)l15*32 + (size_t)grp*8;

    // ---- phase A: LN(x) -> Abuf bf16 (8 rows per wave)
    {
        float4 lg0 = *(const float4*)&lg[lane*8], lg1 = *(const float4*)&lg[lane*8+4];
        float4 lb0 = *(const float4*)&lb[lane*8], lb1 = *(const float4*)&lb[lane*8+4];
        #pragma unroll 2
        for (int rr = 0; rr < 8; ++rr){
            int r = w*8 + rr;
            const float* xp = &x[(size_t)(g0 + r)*D + lane*8];
            float4 v0 = *(const float4*)xp, v1 = *(const float4*)(xp+4);
            float s  = v0.x+v0.y+v0.z+v0.w + v1.x+v1.y+v1.z+v1.w;
            float sq = v0.x*v0.x+v0.y*v0.y+v0.z*v0.z+v0.w*v0.w
                     + v1.x*v1.x+v1.y*v1.y+v1.z*v1.z+v1.w*v1.w;
            #pragma unroll
            for (int o = 32; o; o >>= 1){ s += __shfl_xor(s,o); sq += __shfl_xor(sq,o); }
            float m = s*(1.f/D), var = sq*(1.f/D) - m*m, rstd = rsqrtf(var + 1e-5f);
            bf16x8 ov;
            ov[0] = (bf16)((v0.x-m)*rstd*lg0.x + lb0.x);
            ov[1] = (bf16)((v0.y-m)*rstd*lg0.y + lb0.y);
            ov[2] = (bf16)((v0.z-m)*rstd*lg0.z + lb0.z);
            ov[3] = (bf16)((v0.w-m)*rstd*lg0.w + lb0.w);
            ov[4] = (bf16)((v1.x-m)*rstd*lg1.x + lb1.x);
            ov[5] = (bf16)((v1.y-m)*rstd*lg1.y + lb1.y);
            ov[6] = (bf16)((v1.z-m)*rstd*lg1.z + lb1.z);
            ov[7] = (bf16)((v1.w-m)*rstd*lg1.w + lb1.w);
            *(bf16x8*)&Abuf[r*AS + lane*8] = ov;
        }
    }
    __syncthreads();

    // ---- GEMM1: q = LN(x) @ Wq
    f32x4 acc[2][8];
    #pragma unroll
    for (int mt = 0; mt < 2; ++mt)
        #pragma unroll
        for (int nt = 0; nt < 8; ++nt) acc[mt][nt] = (f32x4){0.f,0.f,0.f,0.f};
    gemm_body(WqS + fragoff, &Abuf[l15*AS + grp*8], acc);

    // ---- softmax per head (two heads per wave, in-register)
    {
        float bqv[8];
        #pragma unroll
        for (int nt = 0; nt < 8; ++nt) bqv[nt] = bq[wb + nt*16 + l15];
        #pragma unroll
        for (int mt = 0; mt < 2; ++mt)
            #pragma unroll
            for (int r = 0; r < 4; ++r)
                #pragma unroll
                for (int hh = 0; hh < 2; ++hh){
                    float v0 = acc[mt][hh*4+0][r] + bqv[hh*4+0];
                    float v1 = acc[mt][hh*4+1][r] + bqv[hh*4+1];
                    float v2 = acc[mt][hh*4+2][r] + bqv[hh*4+2];
                    float v3 = acc[mt][hh*4+3][r] + bqv[hh*4+3];
                    float mx = fmaxf(fmaxf(v0,v1), fmaxf(v2,v3));
                    #pragma unroll
                    for (int o = 1; o < 16; o <<= 1) mx = fmaxf(mx, __shfl_xor(mx, o));
                    float e0 = __expf(v0-mx), e1 = __expf(v1-mx), e2 = __expf(v2-mx), e3 = __expf(v3-mx);
                    float sden = e0+e1+e2+e3;
                    #pragma unroll
                    for (int o = 1; o < 16; o <<= 1) sden += __shfl_xor(sden, o);
                    float inv = 1.f/sden;
                    acc[mt][hh*4+0][r] = e0*inv; acc[mt][hh*4+1][r] = e1*inv;
                    acc[mt][hh*4+2][r] = e2*inv; acc[mt][hh*4+3][r] = e3*inv;
                }
    }
    __syncthreads();   // all waves done reading Abuf (A of GEMM1) before overwrite

    // q (bf16) -> Abuf [all 32 rows][own 128 cols] — wave-local region
    #pragma unroll
    for (int mt = 0; mt < 2; ++mt)
        #pragma unroll
        for (int nt = 0; nt < 8; ++nt)
            #pragma unroll
            for (int r = 0; r < 4; ++r)
                Abuf[(mt*16 + grp*4 + r)*AS + wb + nt*16 + l15] = (bf16)acc[mt][nt][r];
    // wave-local write->read: LDS wait + fence, no block barrier needed (rule #18)
    asm volatile("s_waitcnt lgkmcnt(0)" ::: "memory");
    __builtin_amdgcn_sched_barrier(0);

    // ---- phase D: y = q @ att[heads 2w, 2w+1]
    #pragma unroll
    for (int mt = 0; mt < 2; ++mt)
        #pragma unroll
        for (int nt = 0; nt < 8; ++nt) acc[mt][nt] = (f32x4){0.f,0.f,0.f,0.f};
    #pragma unroll
    for (int hh = 0; hh < 2; ++hh){
        const bf16* ab = attF + (((size_t)b*H + 2*w + hh) << 12);
        bf16x8 bfr[2][4];
        #pragma unroll
        for (int ks = 0; ks < 2; ++ks)
            #pragma unroll
            for (int n4 = 0; n4 < 4; ++n4)
                bfr[ks][n4] = *(const bf16x8*)&ab[(n4*2 + ks)*512 + lane*8];
        #pragma unroll
        for (int ks = 0; ks < 2; ++ks){
            bf16x8 qa[2];
            #pragma unroll
            for (int mt = 0; mt < 2; ++mt)
                qa[mt] = *(const bf16x8*)&Abuf[(mt*16 + l15)*AS + wb + hh*64 + ks*32 + grp*8];
            #pragma unroll
            for (int n4 = 0; n4 < 4; ++n4)
                #pragma unroll
                for (int mt = 0; mt < 2; ++mt)
                    acc[mt][hh*4+n4] = __builtin_amdgcn_mfma_f32_16x16x32_bf16(qa[mt], bfr[ks][n4], acc[mt][hh*4+n4], 0, 0, 0);
        }
    }

    // ---- LN(y) stats: per-wave partials -> LDS -> combine
    #pragma unroll
    for (int mt = 0; mt < 2; ++mt)
        #pragma unroll
        for (int r = 0; r < 4; ++r){
            float s = 0.f, q2 = 0.f;
            #pragma unroll
            for (int nt = 0; nt < 8; ++nt){ float v = acc[mt][nt][r]; s += v; q2 += v*v; }
            #pragma unroll
            for (int o = 1; o < 16; o <<= 1){ s += __shfl_xor(s, o); q2 += __shfl_xor(q2, o); }
            if (l15 == 0){ st_s[mt*16 + grp*4 + r][w] = s; st_q[mt*16 + grp*4 + r][w] = q2; }
        }
    __syncthreads();

    // ---- stylize + silu -> Abuf bf16
    {
        float sgv[8], sbv[8], sscv[8], sshv[8];
        #pragma unroll
        for (int nt = 0; nt < 8; ++nt){
            int col = wb + nt*16 + l15;
            sgv[nt] = sg[col]; sbv[nt] = sb[col];
            sscv[nt] = ssb[b*1024 + col]; sshv[nt] = ssb[b*1024 + 512 + col];
        }
        #pragma unroll
        for (int mt = 0; mt < 2; ++mt)
            #pragma unroll
            for (int r = 0; r < 4; ++r){
                int row = mt*16 + grp*4 + r;
                float4 sv = *(const float4*)&st_s[row][0];
                float4 qv = *(const float4*)&st_q[row][0];
                float m = (sv.x+sv.y+sv.z+sv.w)*(1.f/D);
                float var = (qv.x+qv.y+qv.z+qv.w)*(1.f/D) - m*m;
                float rstd = rsqrtf(var + 1e-5f);
                #pragma unroll
                for (int nt = 0; nt < 8; ++nt){
                    float yn = (acc[mt][nt][r] - m)*rstd*sgv[nt] + sbv[nt];
                    float h2 = yn*(1.f + sscv[nt]) + sshv[nt];
                    Abuf[row*AS + wb + nt*16 + l15] = (bf16)(h2 * sigmoidf_(h2));
                }
            }
    }
    __syncthreads();   // h complete across all waves before GEMM2 reads full K

    // ---- GEMM2: out_pre = silu(h) @ out_W
    #pragma unroll
    for (int mt = 0; mt < 2; ++mt)
        #pragma unroll
        for (int nt = 0; nt < 8; ++nt) acc[mt][nt] = (f32x4){0.f,0.f,0.f,0.f};
    gemm_body(oWS + fragoff, &Abuf[l15*AS + grp*8], acc);

    // ---- epilogue: LDS-bounce (16 rows per half) -> coalesced (acc + ob + x) stores
    float* scr = (float*)Abuf;              // 16 rows x stride 516 f32 = 33024B <= 33280B
    #pragma unroll
    for (int half = 0; half < 2; ++half){
        __syncthreads();    // half0: GEMM2 LDS reads done; half1: prev flush reads done
        #pragma unroll
        for (int nt = 0; nt < 8; ++nt)
            #pragma unroll
            for (int r = 0; r < 4; ++r)
                scr[(grp*4 + r)*516 + wb + nt*16 + l15] = acc[half][nt][r];
        __syncthreads();
        #pragma unroll 2
        for (int i = 0; i < 8; ++i){
            int c = i*256 + t;
            int row = c >> 7, col4 = (c & 127) << 2;
            float4 v  = *(const float4*)&scr[row*516 + col4];
            size_t gi = (size_t)(g0 + half*16 + row)*D + col4;
            float4 xb = *(const float4*)&x[gi];
            float4 o4 = *(const float4*)&ob[col4];
            float4 r4 = {v.x+o4.x+xb.x, v.y+o4.y+xb.y, v.z+o4.z+xb.z, v.w+o4.w+xb.w};
            *(float4*)&out[gi] = r4;
        }
    }
}

extern "C" void kernel_launch(void* const* d_in, const int* in_sizes, int n_in,
                              void* d_out, int out_size, void* d_ws, size_t ws_size,
                              hipStream_t stream){
    const float* x     = (const float*)d_in[0];
    const float* xf    = (const float*)d_in[1];
    const float* emb   = (const float*)d_in[2];
    const float* Wq    = (const float*)d_in[3];
    const float* bq    = (const float*)d_in[4];
    const float* Wk    = (const float*)d_in[5];
    const float* bk    = (const float*)d_in[6];
    const float* Wv    = (const float*)d_in[7];
    const float* bv    = (const float*)d_in[8];
    const float* ln_g  = (const float*)d_in[9];
    const float* ln_b  = (const float*)d_in[10];
    const float* tln_g = (const float*)d_in[11];
    const float* tln_b = (const float*)d_in[12];
    const float* emb_W = (const float*)d_in[13];
    const float* emb_b = (const float*)d_in[14];
    const float* sn_g  = (const float*)d_in[15];
    const float* sn_b  = (const float*)d_in[16];
    const float* out_W = (const float*)d_in[17];
    const float* out_b = (const float*)d_in[18];
    float* out = (float*)d_out;

    // workspace carve
    float* ssb  = (float*)d_ws;                          // B*1024 f32
    bf16*  kbuf = (bf16*)(ssb + B*1024);                 // B*NN*D bf16
    bf16*  vbuf = kbuf + (size_t)B*NN*D;                 // B*NN*D bf16
    bf16*  attF = vbuf + (size_t)B*NN*D;                 // B*H*DH*DH bf16
    bf16*  wqS  = attF + (size_t)B*H*DH*DH;              // D*D bf16 (staged layout)
    bf16*  owS  = wqS  + (size_t)D*D;                    // D*D bf16

    k_prep<<<dim3(448),    dim3(256), 0, stream>>>(Wq, out_W, wqS, owS,
                                                   emb, emb_W, emb_b, ssb,
                                                   xf, Wk, bk, Wv, bv, tln_g, tln_b, kbuf, vbuf);
    k_att <<<dim3(H, B),   dim3(256), 0, stream>>>(kbuf, vbuf, attF);
    k_main<<<dim3(B*T/MR), dim3(256), 0, stream>>>(x, wqS, bq, ln_g, ln_b, attF, ssb,
                                                   sn_g, sn_b, owS, out_b, out);
}